// Round 3
// baseline (1785.158 us; speedup 1.0000x reference)
//
#include <hip/hip_runtime.h>
#include <hip/hip_bf16.h>
#include <math.h>

typedef __hip_bfloat16 bf16;

#define L_SEQ   1024
#define DMODEL  1024
#define DINNER  2048
#define NBATCH  2
#define NCHUNK  16
#define CHLEN   64

__device__ __forceinline__ float b2f(bf16 v) { return __bfloat162float(v); }
__device__ __forceinline__ float ld1(const float* p) { return *p; }
__device__ __forceinline__ float ld1(const bf16* p)  { return b2f(*p); }
__device__ __forceinline__ void st1(float* p, float v) { *p = v; }
__device__ __forceinline__ void st1(bf16* p, float v)  { *p = __float2bfloat16(v); }

enum { EPI_NONE = 0, EPI_SOFTPLUS = 1, EPI_SIGMOID = 2 };

// ---- dtype detector: classify d_in[0] (gaussian data) as f32(0) or packed bf16(1)
__global__ void detect_kernel(const unsigned int* __restrict__ x, int* __restrict__ flag)
{
    int lane = threadIdx.x;  // 64 threads
    int cnt = 0;
    for (int i = 0; i < 16; ++i) {
        unsigned int w = x[lane * 16 + i];
        unsigned int e = (w >> 7) & 0xFFu;  // exponent field of low-half bf16
        cnt += (e >= 115u && e <= 132u) ? 1 : 0;
    }
    for (int off = 32; off; off >>= 1) cnt += __shfl_down(cnt, off);
    if (lane == 0) *flag = (cnt > 512) ? 1 : 0;
}

// C[m][n] = sum_k A[m][k] * W[n][k]   (A row-major MxK via lda, W row-major NxK)
// 64x64 tile, BK=16, 256 threads, 4x4 per thread, fp32 accumulate.
template <typename AT, typename T, typename CT, int EPI, bool REVIN, bool ACCREV>
__global__ __launch_bounds__(256) void gemm_kernel(
    const int* __restrict__ flag, int want,
    const AT* __restrict__ A, const T* __restrict__ W,
    const T* __restrict__ bias, CT* __restrict__ C,
    int N, int K, int lda)
{
    if (*flag != want) return;
    __shared__ float As[16][68];
    __shared__ float Ws[16][68];
    const int tid = threadIdx.x;
    const int tx = tid & 15, ty = tid >> 4;
    const int n0 = blockIdx.x * 64;
    const int m0 = blockIdx.y * 64;
    const int kl = tid & 15, rl = tid >> 4;

    float acc[4][4];
#pragma unroll
    for (int i = 0; i < 4; ++i)
#pragma unroll
        for (int j = 0; j < 4; ++j) acc[i][j] = 0.f;

    for (int k0 = 0; k0 < K; k0 += 16) {
#pragma unroll
        for (int r = 0; r < 4; ++r) {
            int mm = r * 16 + rl;
            int gm = m0 + mm;
            int row = gm;
            if (REVIN) row = (gm & ~(L_SEQ - 1)) + (L_SEQ - 1 - (gm & (L_SEQ - 1)));
            As[kl][mm] = ld1(&A[(size_t)row * lda + k0 + kl]);
            int gn = n0 + mm;
            Ws[kl][mm] = (gn < N) ? ld1(&W[(size_t)gn * K + k0 + kl]) : 0.f;
        }
        __syncthreads();
#pragma unroll
        for (int k = 0; k < 16; ++k) {
            float av[4], wv[4];
#pragma unroll
            for (int i = 0; i < 4; ++i) av[i] = As[k][ty * 4 + i];
#pragma unroll
            for (int j = 0; j < 4; ++j) wv[j] = Ws[k][tx * 4 + j];
#pragma unroll
            for (int i = 0; i < 4; ++i)
#pragma unroll
                for (int j = 0; j < 4; ++j) acc[i][j] += av[i] * wv[j];
        }
        __syncthreads();
    }

#pragma unroll
    for (int i = 0; i < 4; ++i) {
        int gm = m0 + ty * 4 + i;
#pragma unroll
        for (int j = 0; j < 4; ++j) {
            int gn = n0 + tx * 4 + j;
            if (gn >= N) continue;
            float v = acc[i][j];
            if (EPI == EPI_SOFTPLUS) {
                v += ld1(&bias[gn]);
                v = (v > 20.f) ? v : log1pf(expf(v));
            } else if (EPI == EPI_SIGMOID) {
                v = 1.f / (1.f + expf(-v));
            }
            if constexpr (ACCREV) {
                int gmo = (gm & ~(L_SEQ - 1)) + (L_SEQ - 1 - (gm & (L_SEQ - 1)));
                C[(size_t)gmo * N + gn] += v;
            } else {
                st1(&C[(size_t)gm * N + gn], v);
            }
        }
    }
}

// depthwise causal conv(k=4) + bias + silu.  xz: [B*L][4096] bf16 (xi = cols 0..2047)
template <typename T>
__global__ __launch_bounds__(256) void conv_silu_kernel(
    const int* __restrict__ flag, int want,
    const bf16* __restrict__ xz, const T* __restrict__ cw,
    const T* __restrict__ cb, bf16* __restrict__ xic)
{
    if (*flag != want) return;
    int idx = blockIdx.x * 256 + threadIdx.x;
    if (idx >= NBATCH * L_SEQ * DINNER) return;
    int d = idx & (DINNER - 1);
    int m = idx >> 11;
    int l = m & (L_SEQ - 1);
    float w0 = ld1(&cw[d * 4 + 0]), w1 = ld1(&cw[d * 4 + 1]);
    float w2 = ld1(&cw[d * 4 + 2]), w3 = ld1(&cw[d * 4 + 3]);
    float s = ld1(&cb[d]);
    if (l >= 3) s += w0 * b2f(xz[(size_t)(m - 3) * 4096 + d]);
    if (l >= 2) s += w1 * b2f(xz[(size_t)(m - 2) * 4096 + d]);
    if (l >= 1) s += w2 * b2f(xz[(size_t)(m - 1) * 4096 + d]);
    s += w3 * b2f(xz[(size_t)m * 4096 + d]);
    float sl = s / (1.f + expf(-s));  // silu
    xic[idx] = __float2bfloat16(sl);
}

// Pass 1: per (b, chunk, d) run 64-step local scan from h=0; emit h_end and sum(dt).
template <typename T>
__global__ __launch_bounds__(256) void scan_pass1(
    const int* __restrict__ flag, int want,
    const float* __restrict__ dt, const bf16* __restrict__ xic,
    const float* __restrict__ dbc, const T* __restrict__ A_log,
    float* __restrict__ hend, float* __restrict__ sumdt)
{
    if (*flag != want) return;
    int t = blockIdx.x * 256 + threadIdx.x;  // (b*16+c)*2048 + d
    int d = t & (DINNER - 1);
    int bc = t >> 11;
    int c = bc & 15, b = bc >> 4;
    float Av[16];
#pragma unroll
    for (int s = 0; s < 16; ++s) Av[s] = -expf(ld1(&A_log[d * 16 + s]));
    float h[16];
#pragma unroll
    for (int s = 0; s < 16; ++s) h[s] = 0.f;
    float sdt = 0.f;
    int mbase = b * L_SEQ + c * CHLEN;
    for (int l = 0; l < CHLEN; ++l) {
        size_t m = (size_t)(mbase + l);
        float dtv = dt[m * DINNER + d];
        float xiv = b2f(xic[m * DINNER + d]);
        sdt += dtv;
        const float4* bp = (const float4*)&dbc[m * 96 + 64];
        float bb[16];
#pragma unroll
        for (int q = 0; q < 4; ++q) {
            float4 v = bp[q];
            bb[4 * q] = v.x; bb[4 * q + 1] = v.y; bb[4 * q + 2] = v.z; bb[4 * q + 3] = v.w;
        }
        float cxi = dtv * xiv;
#pragma unroll
        for (int s = 0; s < 16; ++s) {
            float a = __expf(dtv * Av[s]);
            h[s] = a * h[s] + cxi * bb[s];
        }
    }
    float* hp = &hend[(((size_t)(b * DINNER + d)) * NCHUNK + c) * 16];
#pragma unroll
    for (int s = 0; s < 16; ++s) hp[s] = h[s];
    sumdt[(b * NCHUNK + c) * DINNER + d] = sdt;
}

// Pass 2: per (b,d,s) combine 16 chunk states sequentially; rewrite hend -> h_start.
template <typename T>
__global__ __launch_bounds__(256) void scan_pass2(
    const int* __restrict__ flag, int want,
    const float* __restrict__ sumdt, const T* __restrict__ A_log,
    float* __restrict__ h)
{
    if (*flag != want) return;
    int t = blockIdx.x * 256 + threadIdx.x;  // (b*2048+d)*16 + s
    int s = t & 15;
    int d = (t >> 4) & (DINNER - 1);
    int b = t >> 15;
    float Av = -expf(ld1(&A_log[d * 16 + s]));
    float run = 0.f;
    size_t base = ((size_t)(b * DINNER + d)) * NCHUNK;
    for (int c = 0; c < NCHUNK; ++c) {
        float sd = sumdt[(b * NCHUNK + c) * DINNER + d];
        float he = h[(base + c) * 16 + s];
        float nxt = __expf(Av * sd) * run + he;
        h[(base + c) * 16 + s] = run;  // h_start for chunk c
        run = nxt;
    }
}

// Pass 3: per (b, chunk, d) rerun scan from h_start, emit gated y into dt buffer.
template <typename T>
__global__ __launch_bounds__(256) void scan_pass3(
    const int* __restrict__ flag, int want,
    float* __restrict__ dty, const bf16* __restrict__ xic,
    const float* __restrict__ dbc, const T* __restrict__ A_log,
    const T* __restrict__ Dp, const bf16* __restrict__ xz,
    const float* __restrict__ hstart)
{
    if (*flag != want) return;
    int t = blockIdx.x * 256 + threadIdx.x;
    int d = t & (DINNER - 1);
    int bc = t >> 11;
    int c = bc & 15, b = bc >> 4;
    float Av[16];
#pragma unroll
    for (int s = 0; s < 16; ++s) Av[s] = -expf(ld1(&A_log[d * 16 + s]));
    float h[16];
    const float* hp = &hstart[(((size_t)(b * DINNER + d)) * NCHUNK + c) * 16];
#pragma unroll
    for (int s = 0; s < 16; ++s) h[s] = hp[s];
    float Dv = ld1(&Dp[d]);
    int mbase = b * L_SEQ + c * CHLEN;
    for (int l = 0; l < CHLEN; ++l) {
        size_t m = (size_t)(mbase + l);
        float dtv = dty[m * DINNER + d];
        float xiv = b2f(xic[m * DINNER + d]);
        const float4* bp = (const float4*)&dbc[m * 96 + 64];
        const float4* cp = (const float4*)&dbc[m * 96 + 80];
        float bb[16], cc[16];
#pragma unroll
        for (int q = 0; q < 4; ++q) {
            float4 v = bp[q];
            bb[4 * q] = v.x; bb[4 * q + 1] = v.y; bb[4 * q + 2] = v.z; bb[4 * q + 3] = v.w;
            float4 w = cp[q];
            cc[4 * q] = w.x; cc[4 * q + 1] = w.y; cc[4 * q + 2] = w.z; cc[4 * q + 3] = w.w;
        }
        float cxi = dtv * xiv;
        float y = 0.f;
#pragma unroll
        for (int s = 0; s < 16; ++s) {
            float a = __expf(dtv * Av[s]);
            h[s] = a * h[s] + cxi * bb[s];
            y += h[s] * cc[s];
        }
        float zv = b2f(xz[m * 4096 + DINNER + d]);
        float sig = 1.f / (1.f + __expf(-zv));
        dty[m * DINNER + d] = (y + xiv * Dv) * (zv * sig);
    }
}

// yo holds yf[m] + yb_rev[m]; d = 0.5*yo; LN + residual, T out
template <typename T>
__global__ __launch_bounds__(256) void ln_kernel(
    const int* __restrict__ flag, int want,
    const float* __restrict__ yo, const T* __restrict__ x,
    const T* __restrict__ g, const T* __restrict__ bta,
    T* __restrict__ out)
{
    if (*flag != want) return;
    __shared__ float red[2][4];
    int m = blockIdx.x;  // b*L + l
    int t = threadIdx.x;
    float v[4];
    float sum = 0.f, sumsq = 0.f;
#pragma unroll
    for (int j = 0; j < 4; ++j) {
        int n = j * 256 + t;
        float dv = 0.5f * yo[(size_t)m * DMODEL + n];
        v[j] = dv;
        sum += dv;
        sumsq += dv * dv;
    }
    for (int off = 32; off; off >>= 1) {
        sum += __shfl_down(sum, off);
        sumsq += __shfl_down(sumsq, off);
    }
    int wave = t >> 6, lane = t & 63;
    if (lane == 0) { red[0][wave] = sum; red[1][wave] = sumsq; }
    __syncthreads();
    if (t == 0) {
        float s0 = 0.f, q0 = 0.f;
        for (int w = 0; w < 4; ++w) { s0 += red[0][w]; q0 += red[1][w]; }
        red[0][0] = s0; red[1][0] = q0;
    }
    __syncthreads();
    float mean = red[0][0] * (1.f / DMODEL);
    float var = red[1][0] * (1.f / DMODEL) - mean * mean;
    float inv = rsqrtf(var + 1e-5f);
#pragma unroll
    for (int j = 0; j < 4; ++j) {
        int n = j * 256 + t;
        float o = (v[j] - mean) * inv * ld1(&g[n]) + ld1(&bta[n]) + ld1(&x[(size_t)m * DMODEL + n]);
        st1(&out[(size_t)m * DMODEL + n], o);
    }
}

struct Ws {
    int*   flag;
    bf16*  xz;   // [B*L][4096]
    bf16*  xic;  // [B*L][2048]
    float* dbc;  // [B*L][96]
    float* dt;   // [B*L][2048]  (dt -> y)
    float* sdt;  // [2][16][2048]
    float* hnd;  // [2][2048][16][16]
    float* yo;   // [B*L][1024]  accumulated over dirs
};

template <typename T, int WANT>
static void run_pipeline(void* const* d_in, void* d_out, const Ws& w, hipStream_t stream)
{
    const T* x    = (const T*)d_in[0];
    const T* ln_g = (const T*)d_in[19];
    const T* ln_b = (const T*)d_in[20];

    for (int dir = 0; dir < 2; ++dir) {
        int o = dir * 9;
        const T* in_proj  = (const T*)d_in[1 + o];
        const T* conv_w   = (const T*)d_in[2 + o];
        const T* conv_b   = (const T*)d_in[3 + o];
        const T* x_proj   = (const T*)d_in[4 + o];
        const T* dt_w     = (const T*)d_in[5 + o];
        const T* dt_b     = (const T*)d_in[6 + o];
        const T* A_log    = (const T*)d_in[7 + o];
        const T* Dp       = (const T*)d_in[8 + o];
        const T* out_proj = (const T*)d_in[9 + o];

        dim3 g1(4096 / 64, 2048 / 64);
        if (dir == 0)
            gemm_kernel<T, T, bf16, EPI_NONE, false, false><<<g1, 256, 0, stream>>>(
                w.flag, WANT, x, in_proj, (const T*)nullptr, w.xz, 4096, 1024, 1024);
        else
            gemm_kernel<T, T, bf16, EPI_NONE, true, false><<<g1, 256, 0, stream>>>(
                w.flag, WANT, x, in_proj, (const T*)nullptr, w.xz, 4096, 1024, 1024);

        conv_silu_kernel<T><<<(NBATCH * L_SEQ * DINNER) / 256, 256, 0, stream>>>(
            w.flag, WANT, w.xz, conv_w, conv_b, w.xic);

        dim3 g2(2, 32);  // N=96
        gemm_kernel<bf16, T, float, EPI_NONE, false, false><<<g2, 256, 0, stream>>>(
            w.flag, WANT, w.xic, x_proj, (const T*)nullptr, w.dbc, 96, 2048, 2048);

        dim3 g3(32, 32);  // N=2048, K=64, lda=96
        gemm_kernel<float, T, float, EPI_SOFTPLUS, false, false><<<g3, 256, 0, stream>>>(
            w.flag, WANT, w.dbc, dt_w, dt_b, w.dt, 2048, 64, 96);

        scan_pass1<T><<<256, 256, 0, stream>>>(w.flag, WANT, w.dt, w.xic, w.dbc, A_log, w.hnd, w.sdt);
        scan_pass2<T><<<256, 256, 0, stream>>>(w.flag, WANT, w.sdt, A_log, w.hnd);
        scan_pass3<T><<<256, 256, 0, stream>>>(w.flag, WANT, w.dt, w.xic, w.dbc, A_log, Dp, w.xz, w.hnd);

        dim3 g4(16, 32);  // N=1024, K=2048
        if (dir == 0)
            gemm_kernel<float, T, float, EPI_SIGMOID, false, false><<<g4, 256, 0, stream>>>(
                w.flag, WANT, w.dt, out_proj, (const T*)nullptr, w.yo, 1024, 2048, 2048);
        else
            gemm_kernel<float, T, float, EPI_SIGMOID, false, true><<<g4, 256, 0, stream>>>(
                w.flag, WANT, w.dt, out_proj, (const T*)nullptr, w.yo, 1024, 2048, 2048);
    }

    ln_kernel<T><<<NBATCH * L_SEQ, 256, 0, stream>>>(w.flag, WANT, w.yo, x, ln_g, ln_b, (T*)d_out);
}

extern "C" void kernel_launch(void* const* d_in, const int* in_sizes, int n_in,
                              void* d_out, int out_size, void* d_ws, size_t ws_size,
                              hipStream_t stream)
{
    char* p = (char*)d_ws;
    Ws w;
    w.flag = (int*)p;    p += 256;
    w.xz   = (bf16*)p;   p += 2048u * 4096u * 2u;          // 16.78 MB
    w.xic  = (bf16*)p;   p += 2048u * 2048u * 2u;          //  8.39 MB
    w.dbc  = (float*)p;  p += 2048u * 96u * 4u;            //  0.79 MB
    w.dt   = (float*)p;  p += 2048u * 2048u * 4u;          // 16.78 MB
    w.sdt  = (float*)p;  p += 2u * 16u * 2048u * 4u;       //  0.26 MB
    w.hnd  = (float*)p;  p += 2u * 2048u * 16u * 16u * 4u; //  4.19 MB
    w.yo   = (float*)p;  p += 2048u * 1024u * 4u;          //  8.39 MB

    detect_kernel<<<1, 64, 0, stream>>>((const unsigned int*)d_in[0], w.flag);

    run_pipeline<float, 0>(d_in, d_out, w, stream);  // fp32 input variant
    run_pipeline<bf16, 1>(d_in, d_out, w, stream);   // bf16 input variant
}

// Round 4
// 713.880 us; speedup vs baseline: 2.5006x; 2.5006x over previous
//
#include <hip/hip_runtime.h>
#include <hip/hip_bf16.h>
#include <math.h>

typedef __hip_bfloat16 bf16;
typedef __attribute__((ext_vector_type(8))) short bfrag;   // 8 bf16
typedef __attribute__((ext_vector_type(4))) float f32x4;

#define L_SEQ   1024
#define DMODEL  1024
#define DINNER  2048
#define NBATCH  2
#define NCHUNK  16
#define CHLEN   64

__device__ __forceinline__ float b2f(bf16 v) { return __bfloat162float(v); }
__device__ __forceinline__ short f2bs(float f) {
    bf16 h = __float2bfloat16(f);
    short s; __builtin_memcpy(&s, &h, 2); return s;
}
__device__ __forceinline__ void st1(float* p, float v) { *p = v; }
__device__ __forceinline__ void st1(bf16* p, float v)  { *p = __float2bfloat16(v); }

enum { EPI_NONE = 0, EPI_SOFTPLUS = 1, EPI_SIGMOID = 2 };

// load 8 elements at p -> 8 bf16-as-short
__device__ __forceinline__ void load8(const float* p, short* d) {
    float4 a = *(const float4*)p;
    float4 b = *(const float4*)(p + 4);
    d[0] = f2bs(a.x); d[1] = f2bs(a.y); d[2] = f2bs(a.z); d[3] = f2bs(a.w);
    d[4] = f2bs(b.x); d[5] = f2bs(b.y); d[6] = f2bs(b.z); d[7] = f2bs(b.w);
}
__device__ __forceinline__ void load8(const bf16* p, short* d) {
    *(uint4*)d = *(const uint4*)p;
}

// C[m][n] = sum_k A[m][k] * W[n][k]; A row-major via lda (fp32 or bf16), W fp32 [N][K].
// 64x64 tile, BK=32, 256 threads (4 waves), MFMA 16x16x32 bf16.
// REVIN: A rows sequence-reversed per L_SEQ batch. ACCREV: C[rev(m)] += v.
template <typename AT, typename CT, int EPI, bool REVIN, bool ACCREV>
__global__ __launch_bounds__(256) void mfma_gemm(
    const AT* __restrict__ A, const float* __restrict__ W,
    const float* __restrict__ bias, CT* __restrict__ C,
    int N, int K, int lda)
{
    __shared__ __align__(16) short As[64][40];   // +8 pad: bank spread
    __shared__ __align__(16) short Ws[64][40];
    const int tid  = threadIdx.x;
    const int lane = tid & 63, wave = tid >> 6;
    const int n0 = blockIdx.x * 64, m0 = blockIdx.y * 64;
    const int srow = tid >> 2;        // 0..63  (staging row)
    const int scol = (tid & 3) * 8;   // 0,8,16,24

    int arow = m0 + srow;
    if (REVIN) arow = (arow & ~(L_SEQ - 1)) + (L_SEQ - 1 - (arow & (L_SEQ - 1)));
    const int wrow = n0 + srow;
    const bool wok = (wrow < N);

    f32x4 acc[4];
#pragma unroll
    for (int i = 0; i < 4; ++i) acc[i] = (f32x4){0.f, 0.f, 0.f, 0.f};

    const int fm = lane & 15;          // fragment row (A) / col (B)
    const int fk = (lane >> 4) * 8;    // fragment k offset

    for (int k0 = 0; k0 < K; k0 += 32) {
        __align__(16) short ta[8], tw[8];
        load8(&A[(size_t)arow * lda + k0 + scol], ta);
        if (wok) load8(&W[(size_t)wrow * K + k0 + scol], tw);
        else {
#pragma unroll
            for (int i = 0; i < 8; ++i) tw[i] = 0;
        }
        *(bfrag*)&As[srow][scol] = *(bfrag*)ta;
        *(bfrag*)&Ws[srow][scol] = *(bfrag*)tw;
        __syncthreads();

        bfrag a = *(const bfrag*)&As[wave * 16 + fm][fk];
#pragma unroll
        for (int nt = 0; nt < 4; ++nt) {
            bfrag b = *(const bfrag*)&Ws[nt * 16 + fm][fk];
            acc[nt] = __builtin_amdgcn_mfma_f32_16x16x32_bf16(a, b, acc[nt], 0, 0, 0);
        }
        __syncthreads();
    }

    // C/D layout: row = (lane>>4)*4 + r, col = lane & 15   [m89-verified]
    const int mrow = wave * 16 + (lane >> 4) * 4;
    const int ncol = lane & 15;
#pragma unroll
    for (int nt = 0; nt < 4; ++nt) {
        int gn = n0 + nt * 16 + ncol;
        if (gn >= N) continue;
        float bv = (EPI == EPI_SOFTPLUS) ? bias[gn] : 0.f;
#pragma unroll
        for (int r = 0; r < 4; ++r) {
            int gm = m0 + mrow + r;
            float v = acc[nt][r];
            if (EPI == EPI_SOFTPLUS) {
                v += bv;
                v = (v > 20.f) ? v : log1pf(expf(v));
            } else if (EPI == EPI_SIGMOID) {
                v = 1.f / (1.f + expf(-v));
            }
            if constexpr (ACCREV) {
                int gmo = (gm & ~(L_SEQ - 1)) + (L_SEQ - 1 - (gm & (L_SEQ - 1)));
                C[(size_t)gmo * N + gn] += v;
            } else {
                st1(&C[(size_t)gm * N + gn], v);
            }
        }
    }
}

// depthwise causal conv(k=4) + bias + silu.  xz: [B*L][4096] bf16 (xi = cols 0..2047)
__global__ __launch_bounds__(256) void conv_silu_kernel(
    const bf16* __restrict__ xz, const float* __restrict__ cw,
    const float* __restrict__ cb, bf16* __restrict__ xic)
{
    int idx = blockIdx.x * 256 + threadIdx.x;
    if (idx >= NBATCH * L_SEQ * DINNER) return;
    int d = idx & (DINNER - 1);
    int m = idx >> 11;
    int l = m & (L_SEQ - 1);
    float w0 = cw[d * 4 + 0], w1 = cw[d * 4 + 1];
    float w2 = cw[d * 4 + 2], w3 = cw[d * 4 + 3];
    float s = cb[d];
    if (l >= 3) s += w0 * b2f(xz[(size_t)(m - 3) * 4096 + d]);
    if (l >= 2) s += w1 * b2f(xz[(size_t)(m - 2) * 4096 + d]);
    if (l >= 1) s += w2 * b2f(xz[(size_t)(m - 1) * 4096 + d]);
    s += w3 * b2f(xz[(size_t)m * 4096 + d]);
    float sl = s / (1.f + expf(-s));  // silu
    xic[idx] = __float2bfloat16(sl);
}

// Pass 1: per (b, chunk, d) run 64-step local scan from h=0; emit h_end and sum(dt).
__global__ __launch_bounds__(256) void scan_pass1(
    const float* __restrict__ dt, const bf16* __restrict__ xic,
    const float* __restrict__ dbc, const float* __restrict__ A_log,
    float* __restrict__ hend, float* __restrict__ sumdt)
{
    int t = blockIdx.x * 256 + threadIdx.x;  // (b*16+c)*2048 + d
    int d = t & (DINNER - 1);
    int bc = t >> 11;
    int c = bc & 15, b = bc >> 4;
    float Av[16];
#pragma unroll
    for (int s = 0; s < 16; ++s) Av[s] = -expf(A_log[d * 16 + s]);
    float h[16];
#pragma unroll
    for (int s = 0; s < 16; ++s) h[s] = 0.f;
    float sdt = 0.f;
    int mbase = b * L_SEQ + c * CHLEN;
    for (int l = 0; l < CHLEN; ++l) {
        size_t m = (size_t)(mbase + l);
        float dtv = dt[m * DINNER + d];
        float xiv = b2f(xic[m * DINNER + d]);
        sdt += dtv;
        const float4* bp = (const float4*)&dbc[m * 96 + 64];
        float bb[16];
#pragma unroll
        for (int q = 0; q < 4; ++q) {
            float4 v = bp[q];
            bb[4 * q] = v.x; bb[4 * q + 1] = v.y; bb[4 * q + 2] = v.z; bb[4 * q + 3] = v.w;
        }
        float cxi = dtv * xiv;
#pragma unroll
        for (int s = 0; s < 16; ++s) {
            float a = __expf(dtv * Av[s]);
            h[s] = a * h[s] + cxi * bb[s];
        }
    }
    float* hp = &hend[(((size_t)(b * DINNER + d)) * NCHUNK + c) * 16];
#pragma unroll
    for (int s = 0; s < 16; ++s) hp[s] = h[s];
    sumdt[(b * NCHUNK + c) * DINNER + d] = sdt;
}

// Pass 2: per (b,d,s) combine 16 chunk states sequentially; rewrite hend -> h_start.
__global__ __launch_bounds__(256) void scan_pass2(
    const float* __restrict__ sumdt, const float* __restrict__ A_log,
    float* __restrict__ h)
{
    int t = blockIdx.x * 256 + threadIdx.x;  // (b*2048+d)*16 + s
    int s = t & 15;
    int d = (t >> 4) & (DINNER - 1);
    int b = t >> 15;
    float Av = -expf(A_log[d * 16 + s]);
    float run = 0.f;
    size_t base = ((size_t)(b * DINNER + d)) * NCHUNK;
    for (int c = 0; c < NCHUNK; ++c) {
        float sd = sumdt[(b * NCHUNK + c) * DINNER + d];
        float he = h[(base + c) * 16 + s];
        float nxt = __expf(Av * sd) * run + he;
        h[(base + c) * 16 + s] = run;  // h_start for chunk c
        run = nxt;
    }
}

// Pass 3: per (b, chunk, d) rerun scan from h_start, emit gated y into dt buffer.
__global__ __launch_bounds__(256) void scan_pass3(
    float* __restrict__ dty, const bf16* __restrict__ xic,
    const float* __restrict__ dbc, const float* __restrict__ A_log,
    const float* __restrict__ Dp, const bf16* __restrict__ xz,
    const float* __restrict__ hstart)
{
    int t = blockIdx.x * 256 + threadIdx.x;
    int d = t & (DINNER - 1);
    int bc = t >> 11;
    int c = bc & 15, b = bc >> 4;
    float Av[16];
#pragma unroll
    for (int s = 0; s < 16; ++s) Av[s] = -expf(A_log[d * 16 + s]);
    float h[16];
    const float* hp = &hstart[(((size_t)(b * DINNER + d)) * NCHUNK + c) * 16];
#pragma unroll
    for (int s = 0; s < 16; ++s) h[s] = hp[s];
    float Dv = Dp[d];
    int mbase = b * L_SEQ + c * CHLEN;
    for (int l = 0; l < CHLEN; ++l) {
        size_t m = (size_t)(mbase + l);
        float dtv = dty[m * DINNER + d];
        float xiv = b2f(xic[m * DINNER + d]);
        const float4* bp = (const float4*)&dbc[m * 96 + 64];
        const float4* cp = (const float4*)&dbc[m * 96 + 80];
        float bb[16], cc[16];
#pragma unroll
        for (int q = 0; q < 4; ++q) {
            float4 v = bp[q];
            bb[4 * q] = v.x; bb[4 * q + 1] = v.y; bb[4 * q + 2] = v.z; bb[4 * q + 3] = v.w;
            float4 w = cp[q];
            cc[4 * q] = w.x; cc[4 * q + 1] = w.y; cc[4 * q + 2] = w.z; cc[4 * q + 3] = w.w;
        }
        float cxi = dtv * xiv;
        float y = 0.f;
#pragma unroll
        for (int s = 0; s < 16; ++s) {
            float a = __expf(dtv * Av[s]);
            h[s] = a * h[s] + cxi * bb[s];
            y += h[s] * cc[s];
        }
        float zv = b2f(xz[m * 4096 + DINNER + d]);
        float sig = 1.f / (1.f + __expf(-zv));
        dty[m * DINNER + d] = (y + xiv * Dv) * (zv * sig);
    }
}

// yo holds yf[m] + yb_rev[m]; d = 0.5*yo; LN + residual, fp32 out
__global__ __launch_bounds__(256) void ln_kernel(
    const float* __restrict__ yo, const float* __restrict__ x,
    const float* __restrict__ g, const float* __restrict__ bta,
    float* __restrict__ out)
{
    __shared__ float red[2][4];
    int m = blockIdx.x;  // b*L + l
    int t = threadIdx.x;
    float v[4];
    float sum = 0.f, sumsq = 0.f;
#pragma unroll
    for (int j = 0; j < 4; ++j) {
        int n = j * 256 + t;
        float dv = 0.5f * yo[(size_t)m * DMODEL + n];
        v[j] = dv;
        sum += dv;
        sumsq += dv * dv;
    }
    for (int off = 32; off; off >>= 1) {
        sum += __shfl_down(sum, off);
        sumsq += __shfl_down(sumsq, off);
    }
    int wave = t >> 6, lane = t & 63;
    if (lane == 0) { red[0][wave] = sum; red[1][wave] = sumsq; }
    __syncthreads();
    if (t == 0) {
        float s0 = 0.f, q0 = 0.f;
        for (int w = 0; w < 4; ++w) { s0 += red[0][w]; q0 += red[1][w]; }
        red[0][0] = s0; red[1][0] = q0;
    }
    __syncthreads();
    float mean = red[0][0] * (1.f / DMODEL);
    float var = red[1][0] * (1.f / DMODEL) - mean * mean;
    float inv = rsqrtf(var + 1e-5f);
#pragma unroll
    for (int j = 0; j < 4; ++j) {
        int n = j * 256 + t;
        float o = (v[j] - mean) * inv * g[n] + bta[n] + x[(size_t)m * DMODEL + n];
        out[(size_t)m * DMODEL + n] = o;
    }
}

extern "C" void kernel_launch(void* const* d_in, const int* in_sizes, int n_in,
                              void* d_out, int out_size, void* d_ws, size_t ws_size,
                              hipStream_t stream)
{
    const float* x    = (const float*)d_in[0];
    const float* ln_g = (const float*)d_in[19];
    const float* ln_b = (const float*)d_in[20];

    char* p = (char*)d_ws;
    bf16*  xz  = (bf16*)p;   p += 2048u * 4096u * 2u;          // 16.78 MB [B*L][4096]
    bf16*  xic = (bf16*)p;   p += 2048u * 2048u * 2u;          //  8.39 MB [B*L][2048]
    float* dbc = (float*)p;  p += 2048u * 96u * 4u;            //  0.79 MB [B*L][96]
    float* dt  = (float*)p;  p += 2048u * 2048u * 4u;          // 16.78 MB [B*L][2048]
    float* sdt = (float*)p;  p += 2u * 16u * 2048u * 4u;       //  0.26 MB
    float* hnd = (float*)p;  p += 2u * 2048u * 16u * 16u * 4u; //  4.19 MB
    float* yo  = (float*)p;  p += 2048u * 1024u * 4u;          //  8.39 MB

    for (int dir = 0; dir < 2; ++dir) {
        int o = dir * 9;
        const float* in_proj  = (const float*)d_in[1 + o];
        const float* conv_w   = (const float*)d_in[2 + o];
        const float* conv_b   = (const float*)d_in[3 + o];
        const float* x_proj   = (const float*)d_in[4 + o];
        const float* dt_w     = (const float*)d_in[5 + o];
        const float* dt_b     = (const float*)d_in[6 + o];
        const float* A_log    = (const float*)d_in[7 + o];
        const float* Dp       = (const float*)d_in[8 + o];
        const float* out_proj = (const float*)d_in[9 + o];

        dim3 g1(4096 / 64, 2048 / 64);
        if (dir == 0)
            mfma_gemm<float, bf16, EPI_NONE, false, false><<<g1, 256, 0, stream>>>(
                x, in_proj, nullptr, xz, 4096, 1024, 1024);
        else
            mfma_gemm<float, bf16, EPI_NONE, true, false><<<g1, 256, 0, stream>>>(
                x, in_proj, nullptr, xz, 4096, 1024, 1024);

        conv_silu_kernel<<<(NBATCH * L_SEQ * DINNER) / 256, 256, 0, stream>>>(
            xz, conv_w, conv_b, xic);

        dim3 g2(2, 32);  // N=96 (guarded)
        mfma_gemm<bf16, float, EPI_NONE, false, false><<<g2, 256, 0, stream>>>(
            xic, x_proj, nullptr, dbc, 96, 2048, 2048);

        dim3 g3(32, 32);  // N=2048, K=64, lda=96
        mfma_gemm<float, float, EPI_SOFTPLUS, false, false><<<g3, 256, 0, stream>>>(
            dbc, dt_w, dt_b, dt, 2048, 64, 96);

        scan_pass1<<<256, 256, 0, stream>>>(dt, xic, dbc, A_log, hnd, sdt);
        scan_pass2<<<256, 256, 0, stream>>>(sdt, A_log, hnd);
        scan_pass3<<<256, 256, 0, stream>>>(dt, xic, dbc, A_log, Dp, xz, hnd);

        dim3 g4(16, 32);  // N=1024, K=2048
        if (dir == 0)
            mfma_gemm<float, float, EPI_SIGMOID, false, false><<<g4, 256, 0, stream>>>(
                dt, out_proj, nullptr, yo, 1024, 2048, 2048);
        else
            mfma_gemm<float, float, EPI_SIGMOID, false, true><<<g4, 256, 0, stream>>>(
                dt, out_proj, nullptr, yo, 1024, 2048, 2048);
    }

    ln_kernel<<<NBATCH * L_SEQ, 256, 0, stream>>>(yo, x, ln_g, ln_b, (float*)d_out);
}